// Round 5
// baseline (1145.136 us; speedup 1.0000x reference)
//
#include <hip/hip_runtime.h>
#include <math.h>

#define NN    100000
#define GG    100
#define FIN   12
#define FOUT  32
#define KD    5
#define CC    4
#define EE    1600000
#define ROWS  108          // 9 blocks * 12 features
#define NBF   782          // fwd coarse bins (128 nodes each; last has 96)
#define NBINS 1564         // fwd bins + rev bins
#define NBC   128          // blocks in the coarse build (EE/NBC = 12500 exact)
#define CHUNK 12500

// ---------------- utility ----------------

__global__ void k_zero(int* __restrict__ p, int n) {
    int i = blockIdx.x * 256 + threadIdx.x;
    if (i < n) p[i] = 0;
}

// ---------------- coarse-bucket CSR build ----------------
// Bin layout: bin_f = dst>>7 in [0,NBF); bin_r = NBF + (src>>7).
// Record: .x = nbr | (local_node << 17)   (nbr < 2^17, local < 128)
//         .y = edge weight (raw; fwd region rewritten to coef by k_coef)

// P1: per-block LDS histogram -> ~NBC*NBINS global atomics (bin-granular).
__global__ __launch_bounds__(256) void k_hist(const int* __restrict__ ei,
                                              int* __restrict__ gcnt) {
    __shared__ int hist[NBINS];
    for (int i = threadIdx.x; i < NBINS; i += 256) hist[i] = 0;
    __syncthreads();
    int lo = blockIdx.x * CHUNK, hi = lo + CHUNK;
    for (int e = lo + threadIdx.x; e < hi; e += 256) {
        int s = ei[e], d = ei[EE + e];
        atomicAdd(&hist[d >> 7], 1);
        atomicAdd(&hist[NBF + (s >> 7)], 1);
    }
    __syncthreads();
    for (int i = threadIdx.x; i < NBINS; i += 256)
        if (hist[i]) atomicAdd(&gcnt[i], hist[i]);
}

// P2: one-block exclusive scan of gcnt[0..NBINS) -> off[0..NBINS], seed gcur.
__global__ __launch_bounds__(1024) void k_scan(const int* __restrict__ gcnt,
                                               int* __restrict__ off,
                                               int* __restrict__ gcur) {
    __shared__ int sh[1024];
    int t = threadIdx.x;
    int a = (2 * t     < NBINS) ? gcnt[2 * t]     : 0;
    int b = (2 * t + 1 < NBINS) ? gcnt[2 * t + 1] : 0;
    int s = a + b;
    sh[t] = s;
    __syncthreads();
    for (int d = 1; d < 1024; d <<= 1) {
        int add = (t >= d) ? sh[t - d] : 0;
        __syncthreads();
        sh[t] += add;
        __syncthreads();
    }
    int base = sh[t] - s;  // exclusive over pairs
    if (2 * t < NBINS)     { off[2 * t] = base;         gcur[2 * t] = base; }
    if (2 * t + 1 < NBINS) { off[2 * t + 1] = base + a; gcur[2 * t + 1] = base + a; }
    if (t == 1023) off[NBINS] = sh[1023];
}

// P3: re-histogram, allocate per-(block,bin) bases globally, rank via LDS
// returning atomics, write records in contiguous per-bin runs.
__global__ __launch_bounds__(256) void k_place(const int* __restrict__ ei,
                                               const float* __restrict__ ew,
                                               int* __restrict__ gcur,
                                               int2* __restrict__ rec) {
    __shared__ int hist[NBINS];
    __shared__ int cur[NBINS];
    for (int i = threadIdx.x; i < NBINS; i += 256) hist[i] = 0;
    __syncthreads();
    int lo = blockIdx.x * CHUNK, hi = lo + CHUNK;
    for (int e = lo + threadIdx.x; e < hi; e += 256) {
        int s = ei[e], d = ei[EE + e];
        atomicAdd(&hist[d >> 7], 1);
        atomicAdd(&hist[NBF + (s >> 7)], 1);
    }
    __syncthreads();
    for (int i = threadIdx.x; i < NBINS; i += 256) {
        int c = hist[i];
        if (c) cur[i] = atomicAdd(&gcur[i], c);
    }
    __syncthreads();
    for (int e = lo + threadIdx.x; e < hi; e += 256) {
        int s = ei[e], d = ei[EE + e];
        float w = ew[e];
        int pf = atomicAdd(&cur[d >> 7], 1);
        rec[pf] = make_int2(s | ((d & 127) << 17), __float_as_int(w));
        int pr = atomicAdd(&cur[NBF + (s >> 7)], 1);
        rec[pr] = make_int2(d | ((s & 127) << 17), __float_as_int(w));
    }
}

// P4: per-bucket weighted degree sums via LDS float atomics -> 1/deg.
// fwd bucket (keyed by dst) -> deg_in; rev bucket (keyed by src) -> deg_out.
__global__ __launch_bounds__(256) void k_deginv(const int* __restrict__ off,
                                                const int2* __restrict__ rec,
                                                float* __restrict__ dinv_in,
                                                float* __restrict__ dinv_out) {
    __shared__ float acc[128];
    int b = blockIdx.x;
    if (threadIdx.x < 128) acc[threadIdx.x] = 0.f;
    __syncthreads();
    int e0 = off[b], e1 = off[b + 1];
    for (int e = e0 + threadIdx.x; e < e1; e += 256) {
        int2 r = rec[e];
        atomicAdd(&acc[r.x >> 17], __int_as_float(r.y));
    }
    __syncthreads();
    if (threadIdx.x < 128) {
        bool rev = b >= NBF;
        int node = (rev ? b - NBF : b) * 128 + threadIdx.x;
        if (node < NN) {
            float v = 1.f / acc[threadIdx.x];
            if (rev) dinv_out[node] = v;
            else     dinv_in[node]  = v;
        }
    }
}

// P5: rewrite fwd-region payload (rec[0..EE)) to coef = 1/deg_out[src].
__global__ void k_coef(int2* __restrict__ rec, const float* __restrict__ dinv_out) {
    int e = blockIdx.x * 256 + threadIdx.x;
    if (e >= EE) return;
    rec[e].y = __float_as_int(dinv_out[rec[e].x & 0x1FFFF]);
}

// ---------------- weights ----------------

// Collapse W[2,K,44,32] -> effective [108,32] (only first 12 input rows matter;
// block 0 = W[0,0]+W[1,0]; blocks 1..4 = W[0,k]; blocks 5..8 = W[1,k]).
__global__ void k_buildw(const float* __restrict__ Wz_in, const float* __restrict__ Wh_in,
                         float* __restrict__ Wz, float* __restrict__ Wh) {
    int t = blockIdx.x * 256 + threadIdx.x;
    if (t >= 2 * ROWS * FOUT) return;
    int sel = t / (ROWS * FOUT);
    int rem = t - sel * ROWS * FOUT;
    int r = rem / FOUT;
    int f = rem - r * FOUT;
    int b = r / 12;
    int i = r - b * 12;
    const float* Ws = sel ? Wh_in : Wz_in;
    float v;
    if (b == 0)
        v = Ws[(0 * KD + 0) * 44 * 32 + i * 32 + f] + Ws[(1 * KD + 0) * 44 * 32 + i * 32 + f];
    else if (b <= 4)
        v = Ws[(0 * KD + b) * 44 * 32 + i * 32 + f];
    else
        v = Ws[(1 * KD + (b - 4)) * 44 * 32 + i * 32 + f];
    (sel ? Wh : Wz)[r * FOUT + f] = v;
}

// ---------------- diffusion gather (bucket-per-block, LDS accumulate) ----------------
// fwd bucket b:      out[node] = c * sum coef(src)*in[src]        - prev[node]
// rev bucket b-NBF:  out[node] = c * dinv_in[node] * sum in[dst]  - prev[node]
__global__ __launch_bounds__(256) void k_gather(
        const int* __restrict__ off, const int2* __restrict__ rec,
        const float* __restrict__ inF, const float* __restrict__ inR,
        const float* __restrict__ prevF, const float* __restrict__ prevR,
        const float* __restrict__ dinv_in,
        float* __restrict__ outF, float* __restrict__ outR, float c) {
    __shared__ __align__(16) float acc[128 * FIN];
    int b = blockIdx.x;
    bool rev = b >= NBF;
    int t = threadIdx.x;
    for (int i = t; i < 128 * FIN; i += 256) acc[i] = 0.f;
    __syncthreads();

    int e0 = off[b], e1 = off[b + 1];
    const float* in = rev ? inR : inF;
    for (int e = e0 + t; e < e1; e += 256) {
        int2 r = rec[e];
        int nbr = r.x & 0x1FFFF;
        float* a = acc + (r.x >> 17) * FIN;
        const float4* row = (const float4*)(in + (size_t)nbr * FIN);
        float4 x0 = row[0], x1 = row[1], x2 = row[2];
        if (rev) {
            atomicAdd(a + 0,  x0.x); atomicAdd(a + 1,  x0.y);
            atomicAdd(a + 2,  x0.z); atomicAdd(a + 3,  x0.w);
            atomicAdd(a + 4,  x1.x); atomicAdd(a + 5,  x1.y);
            atomicAdd(a + 6,  x1.z); atomicAdd(a + 7,  x1.w);
            atomicAdd(a + 8,  x2.x); atomicAdd(a + 9,  x2.y);
            atomicAdd(a + 10, x2.z); atomicAdd(a + 11, x2.w);
        } else {
            float w = __int_as_float(r.y);
            atomicAdd(a + 0,  w * x0.x); atomicAdd(a + 1,  w * x0.y);
            atomicAdd(a + 2,  w * x0.z); atomicAdd(a + 3,  w * x0.w);
            atomicAdd(a + 4,  w * x1.x); atomicAdd(a + 5,  w * x1.y);
            atomicAdd(a + 6,  w * x1.z); atomicAdd(a + 7,  w * x1.w);
            atomicAdd(a + 8,  w * x2.x); atomicAdd(a + 9,  w * x2.y);
            atomicAdd(a + 10, w * x2.z); atomicAdd(a + 11, w * x2.w);
        }
    }
    __syncthreads();

    int base = (rev ? b - NBF : b) * 128;
    const float* prev = rev ? prevR : prevF;
    float* out = rev ? outR : outF;
    for (int i = t; i < 128 * 3; i += 256) {
        int loc = i / 3, ch = i - loc * 3;
        int node = base + loc;
        if (node >= NN) continue;
        float sc = rev ? c * dinv_in[node] : c;
        float4 v = *(const float4*)(acc + loc * FIN + ch * 4);
        v.x *= sc; v.y *= sc; v.z *= sc; v.w *= sc;
        size_t o = (size_t)node * FIN + ch * 4;
        if (prevF) {
            float4 p = *(const float4*)(prev + o);
            v.x -= p.x; v.y -= p.y; v.z -= p.z; v.w -= p.w;
        }
        *(float4*)(out + o) = v;
    }
}

// ---------------- epilogue ----------------

__global__ void k_init_out(float* __restrict__ out, const float* __restrict__ b_lin) {
    int t = blockIdx.x * 256 + threadIdx.x;
    if (t < GG * CC) out[t] = b_lin[t & 3];
}

// Per-node: [1x108] @ [108x32] for z and h_tilde, gate, ReLU, @W_lin,
// block-reduce over 250 nodes (each block owns 1/4 of one graph) -> atomicAdd.
__global__ __launch_bounds__(256) void k_fused(
        const float* __restrict__ x, const float* __restrict__ TS,
        const float* __restrict__ Wz, const float* __restrict__ Wh,
        const float* __restrict__ bz, const float* __restrict__ bh,
        const float* __restrict__ Wlin, float* __restrict__ out) {
    int g = blockIdx.x >> 2;
    int seg = blockIdx.x & 3;
    int tid = threadIdx.x;
    int node = g * 1000 + seg * 250 + tid;
    bool active = tid < 250;

    float az[FOUT], ah[FOUT];
#pragma unroll
    for (int f = 0; f < FOUT; ++f) { az[f] = bz[f]; ah[f] = bh[f]; }
    float o[CC] = {0.f, 0.f, 0.f, 0.f};

    if (active) {
        for (int b = 0; b < 9; ++b) {
            const float* row = (b == 0) ? (x + (size_t)node * FIN)
                                        : (TS + ((size_t)(b - 1) * NN + node) * FIN);
            float4 r0 = *(const float4*)(row);
            float4 r1 = *(const float4*)(row + 4);
            float4 r2 = *(const float4*)(row + 8);
            float rv[FIN] = {r0.x, r0.y, r0.z, r0.w, r1.x, r1.y, r1.z, r1.w,
                             r2.x, r2.y, r2.z, r2.w};
            const float* wzr = Wz + b * 12 * FOUT;
            const float* whr = Wh + b * 12 * FOUT;
#pragma unroll
            for (int i = 0; i < FIN; ++i) {
                float v = rv[i];
#pragma unroll
                for (int f = 0; f < FOUT; ++f) {
                    az[f] = fmaf(v, wzr[i * FOUT + f], az[f]);
                    ah[f] = fmaf(v, whr[i * FOUT + f], ah[f]);
                }
            }
        }
#pragma unroll
        for (int f = 0; f < FOUT; ++f) {
            float z = 1.f / (1.f + __expf(-az[f]));
            float e2 = __expf(2.f * ah[f]);
            float th = 1.f - 2.f / (e2 + 1.f);   // tanh, overflow-safe
            float hv = (1.f - z) * th;
            hv = fmaxf(hv, 0.f);
#pragma unroll
            for (int c = 0; c < CC; ++c) o[c] = fmaf(hv, Wlin[f * 4 + c], o[c]);
        }
    }

    __shared__ float red[256 * CC];
#pragma unroll
    for (int c = 0; c < CC; ++c) red[tid * CC + c] = o[c];
    __syncthreads();
    for (int st = 128; st > 0; st >>= 1) {
        if (tid < st) {
#pragma unroll
            for (int c = 0; c < CC; ++c) red[tid * CC + c] += red[(tid + st) * CC + c];
        }
        __syncthreads();
    }
    if (tid == 0) {
#pragma unroll
        for (int c = 0; c < CC; ++c) atomicAdd(out + g * CC + c, red[c] * 0.001f);
    }
}

// ---------------- launch ----------------

extern "C" void kernel_launch(void* const* d_in, const int* in_sizes, int n_in,
                              void* d_out, int out_size, void* d_ws, size_t ws_size,
                              hipStream_t stream) {
    const float* x     = (const float*)d_in[0];
    const int*   ei    = (const int*)d_in[1];
    const float* ew    = (const float*)d_in[2];
    // d_in[3] (batch) unused: graphs are exactly 1000 contiguous nodes
    const float* W_z   = (const float*)d_in[4];
    const float* b_z   = (const float*)d_in[5];
    // d_in[6], d_in[7] (W_r, b_r) unused: R only multiplies the zero hidden state
    const float* W_h   = (const float*)d_in[8];
    const float* b_h   = (const float*)d_in[9];
    const float* W_lin = (const float*)d_in[10];
    const float* b_lin = (const float*)d_in[11];
    float* out = (float*)d_out;

    // ---- workspace layout (~64.9 MB) ----
    int2*  rec      = (int2*)d_ws;                      // 2*EE records (25.6 MB)
    float* TS       = (float*)(rec + 2 * (size_t)EE);   // 8*N*12 floats (38.4 MB)
    float* dinv_in  = TS + (size_t)8 * NN * FIN;        // N
    float* dinv_out = dinv_in + NN;                     // N
    float* Wz       = dinv_out + NN;                    // 108*32
    float* Wh       = Wz + ROWS * FOUT;                 // 108*32
    int*   off      = (int*)(Wh + ROWS * FOUT);         // NBINS+1
    int*   gcnt     = off + NBINS + 1;                  // NBINS
    int*   gcur     = gcnt + NBINS;                     // NBINS

    float* T1o = TS + (size_t)0 * NN * FIN;
    float* T2o = TS + (size_t)1 * NN * FIN;
    float* T3o = TS + (size_t)2 * NN * FIN;
    float* T4o = TS + (size_t)3 * NN * FIN;
    float* T1i = TS + (size_t)4 * NN * FIN;
    float* T2i = TS + (size_t)5 * NN * FIN;
    float* T3i = TS + (size_t)6 * NN * FIN;
    float* T4i = TS + (size_t)7 * NN * FIN;

    dim3 B(256);
    int nbE = (EE + 255) / 256;

    k_zero<<<(NBINS + 255) / 256, B, 0, stream>>>(gcnt, NBINS);
    k_hist<<<NBC, B, 0, stream>>>(ei, gcnt);
    k_scan<<<1, 1024, 0, stream>>>(gcnt, off, gcur);
    k_place<<<NBC, B, 0, stream>>>(ei, ew, gcur, rec);
    k_deginv<<<NBINS, B, 0, stream>>>(off, rec, dinv_in, dinv_out);
    k_coef<<<nbE, B, 0, stream>>>(rec, dinv_out);

    k_buildw<<<(2 * ROWS * FOUT + 255) / 256, B, 0, stream>>>(W_z, W_h, Wz, Wh);

    // Chebyshev diffusion basis (bucket-parallel, LDS-accumulated)
    k_gather<<<NBINS, B, 0, stream>>>(off, rec, x, x, nullptr, nullptr, dinv_in, T1o, T1i, 1.f);
    k_gather<<<NBINS, B, 0, stream>>>(off, rec, T1o, T1i, x, x, dinv_in, T2o, T2i, 2.f);
    k_gather<<<NBINS, B, 0, stream>>>(off, rec, T2o, T2i, T1o, T1i, dinv_in, T3o, T3i, 2.f);
    k_gather<<<NBINS, B, 0, stream>>>(off, rec, T3o, T3i, T2o, T2i, dinv_in, T4o, T4i, 2.f);

    k_init_out<<<(GG * CC + 255) / 256, B, 0, stream>>>(out, b_lin);
    k_fused<<<4 * GG, B, 0, stream>>>(x, TS, Wz, Wh, b_z, b_h, W_lin, out);
}

// Round 6
// 544.180 us; speedup vs baseline: 2.1043x; 2.1043x over previous
//
#include <hip/hip_runtime.h>
#include <math.h>

#define NN    100000
#define GG    100
#define FIN   12
#define FOUT  32
#define KD    5
#define CC    4
#define EE    1600000
#define ROWS  108          // 9 blocks * 12 features
#define NBF   782          // fwd coarse bins (128 nodes each; last has 96)
#define NBINS 1564         // fwd bins + rev bins
#define NBC   128          // blocks in the coarse build (EE/NBC = 12500 exact)
#define CHUNK 12500

// ---------------- utility ----------------

__global__ void k_zero(int* __restrict__ p, int n) {
    int i = blockIdx.x * 256 + threadIdx.x;
    if (i < n) p[i] = 0;
}

// ---------------- coarse-bucket CSR build ----------------
// Bin layout: bin_f = dst>>7 in [0,NBF); bin_r = NBF + (src>>7).
// recA: .x = nbr | (local_node << 17)  (nbr < 2^17, local < 128), .y = edge weight.

// P1: per-block LDS histogram -> bin-granular global atomics only.
__global__ __launch_bounds__(256) void k_hist(const int* __restrict__ ei,
                                              int* __restrict__ gcnt) {
    __shared__ int hist[NBINS];
    for (int i = threadIdx.x; i < NBINS; i += 256) hist[i] = 0;
    __syncthreads();
    int lo = blockIdx.x * CHUNK, hi = lo + CHUNK;
    for (int e = lo + threadIdx.x; e < hi; e += 256) {
        int s = ei[e], d = ei[EE + e];
        atomicAdd(&hist[d >> 7], 1);
        atomicAdd(&hist[NBF + (s >> 7)], 1);
    }
    __syncthreads();
    for (int i = threadIdx.x; i < NBINS; i += 256)
        if (hist[i]) atomicAdd(&gcnt[i], hist[i]);
}

// P2: one-block exclusive scan of gcnt -> off[0..NBINS], seed gcur,
// and terminate the per-node offset array.
__global__ __launch_bounds__(1024) void k_scan(const int* __restrict__ gcnt,
                                               int* __restrict__ off,
                                               int* __restrict__ gcur,
                                               int* __restrict__ off_node) {
    __shared__ int sh[1024];
    int t = threadIdx.x;
    int a = (2 * t     < NBINS) ? gcnt[2 * t]     : 0;
    int b = (2 * t + 1 < NBINS) ? gcnt[2 * t + 1] : 0;
    int s = a + b;
    sh[t] = s;
    __syncthreads();
    for (int d = 1; d < 1024; d <<= 1) {
        int add = (t >= d) ? sh[t - d] : 0;
        __syncthreads();
        sh[t] += add;
        __syncthreads();
    }
    int base = sh[t] - s;  // exclusive over pairs
    if (2 * t < NBINS)     { off[2 * t] = base;         gcur[2 * t] = base; }
    if (2 * t + 1 < NBINS) { off[2 * t + 1] = base + a; gcur[2 * t + 1] = base + a; }
    if (t == 1023) { off[NBINS] = sh[1023]; off_node[2 * NN] = sh[1023]; }
}

// P3: re-histogram, allocate per-(block,bin) bases, rank via LDS returning
// atomics, write records in contiguous per-bin runs.
__global__ __launch_bounds__(256) void k_place(const int* __restrict__ ei,
                                               const float* __restrict__ ew,
                                               int* __restrict__ gcur,
                                               int2* __restrict__ recA) {
    __shared__ int hist[NBINS];
    __shared__ int cur[NBINS];
    for (int i = threadIdx.x; i < NBINS; i += 256) hist[i] = 0;
    __syncthreads();
    int lo = blockIdx.x * CHUNK, hi = lo + CHUNK;
    for (int e = lo + threadIdx.x; e < hi; e += 256) {
        int s = ei[e], d = ei[EE + e];
        atomicAdd(&hist[d >> 7], 1);
        atomicAdd(&hist[NBF + (s >> 7)], 1);
    }
    __syncthreads();
    for (int i = threadIdx.x; i < NBINS; i += 256) {
        int c = hist[i];
        if (c) cur[i] = atomicAdd(&gcur[i], c);
    }
    __syncthreads();
    for (int e = lo + threadIdx.x; e < hi; e += 256) {
        int s = ei[e], d = ei[EE + e];
        float w = ew[e];
        int pf = atomicAdd(&cur[d >> 7], 1);
        recA[pf] = make_int2(s | ((d & 127) << 17), __float_as_int(w));
        int pr = atomicAdd(&cur[NBF + (s >> 7)], 1);
        recA[pr] = make_int2(d | ((s & 127) << 17), __float_as_int(w));
    }
}

// P4: per-bin counting sort by local node -> exact per-node CSR (4B records),
// fused weighted-degree sums -> dinv, and (rev bins) gA = dinv_out .* x.
__global__ __launch_bounds__(256) void k_subcsr(
        const int* __restrict__ off, const int2* __restrict__ recA,
        const float* __restrict__ x,
        int* __restrict__ off_node, int* __restrict__ rec2,
        float* __restrict__ dinv_in, float* __restrict__ dinv_out,
        float* __restrict__ gA) {
    __shared__ int   hist[128];
    __shared__ int   lofs[128];
    __shared__ int   cur[128];
    __shared__ float wsum[128];
    __shared__ float dl[128];
    int b = blockIdx.x;
    int t = threadIdx.x;
    if (t < 128) { hist[t] = 0; wsum[t] = 0.f; }
    __syncthreads();
    int e0 = off[b], e1 = off[b + 1];
    for (int e = e0 + t; e < e1; e += 256) {
        int2 r = recA[e];
        int loc = r.x >> 17;
        atomicAdd(&hist[loc], 1);
        atomicAdd(&wsum[loc], __int_as_float(r.y));
    }
    __syncthreads();
    if (t < 128) lofs[t] = hist[t];
    __syncthreads();
    for (int d = 1; d < 128; d <<= 1) {
        int v = 0;
        if (t < 128 && t >= d) v = lofs[t - d];
        __syncthreads();
        if (t < 128) lofs[t] += v;
        __syncthreads();
    }
    bool rev = b >= NBF;
    int base = (rev ? b - NBF : b) * 128;
    if (t < 128) {
        int ex = lofs[t] - hist[t];      // exclusive
        lofs[t] = ex;
        cur[t] = 0;
        int node = base + t;
        if (node < NN) {
            off_node[(rev ? NN : 0) + node] = e0 + ex;
            float inv = 1.f / wsum[t];
            dl[t] = inv;
            if (rev) dinv_out[node] = inv;
            else     dinv_in[node]  = inv;
        }
    }
    __syncthreads();
    for (int e = e0 + t; e < e1; e += 256) {
        int rx = recA[e].x;
        int loc = rx >> 17;
        int pos = e0 + lofs[loc] + atomicAdd(&cur[loc], 1);
        rec2[pos] = rx & 0x1FFFF;
    }
    if (rev) {
        __syncthreads();
        for (int i = t; i < 128 * 3; i += 256) {
            int loc = i / 3, ch = i - loc * 3;
            int node = base + loc;
            if (node < NN) {
                float4 v = *(const float4*)(x + (size_t)node * FIN + ch * 4);
                float sc = dl[loc];
                v.x *= sc; v.y *= sc; v.z *= sc; v.w *= sc;
                *(float4*)(gA + (size_t)node * FIN + ch * 4) = v;
            }
        }
    }
}

// ---------------- weights ----------------

// Collapse W[2,K,44,32] -> effective [108,32] (only first 12 input rows matter;
// block 0 = W[0,0]+W[1,0]; blocks 1..4 = W[0,k]; blocks 5..8 = W[1,k]).
__global__ void k_buildw(const float* __restrict__ Wz_in, const float* __restrict__ Wh_in,
                         float* __restrict__ Wz, float* __restrict__ Wh) {
    int t = blockIdx.x * 256 + threadIdx.x;
    if (t >= 2 * ROWS * FOUT) return;
    int sel = t / (ROWS * FOUT);
    int rem = t - sel * ROWS * FOUT;
    int r = rem / FOUT;
    int f = rem - r * FOUT;
    int b = r / 12;
    int i = r - b * 12;
    const float* Ws = sel ? Wh_in : Wz_in;
    float v;
    if (b == 0)
        v = Ws[(0 * KD + 0) * 44 * 32 + i * 32 + f] + Ws[(1 * KD + 0) * 44 * 32 + i * 32 + f];
    else if (b <= 4)
        v = Ws[(0 * KD + b) * 44 * 32 + i * 32 + f];
    else
        v = Ws[(1 * KD + (b - 4)) * 44 * 32 + i * 32 + f];
    (sel ? Wh : Wz)[r * FOUT + f] = v;
}

// ---------------- diffusion gather ----------------
// Thread per (node, direction, 4-feature chunk); 4B records, no weights:
// fwd: out[n] = c * sum gIn[src]                 - prevF[n];  gOut[n] = dinv_out[n]*out[n]
// rev: out[n] = c * dinv_in[n] * sum hIn[dst]    - prevR[n]
__global__ __launch_bounds__(256) void k_gather(
        const int* __restrict__ off_node, const int* __restrict__ rec2,
        const float* __restrict__ gIn, const float* __restrict__ hIn,
        const float* __restrict__ prevF, const float* __restrict__ prevR,
        const float* __restrict__ dinv_in, const float* __restrict__ dinv_out,
        float* __restrict__ outF, float* __restrict__ outR,
        float* __restrict__ gOut, float c) {
    int gid = blockIdx.x * 256 + threadIdx.x;
    if (gid >= 6 * NN) return;
    bool rev = gid >= 3 * NN;
    int t = rev ? gid - 3 * NN : gid;
    int node = t / 3;
    int ch = t - node * 3;
    int i0 = (rev ? NN : 0) + node;
    int e0 = off_node[i0], e1 = off_node[i0 + 1];
    const float* in = rev ? hIn : gIn;

    float ax = 0.f, ay = 0.f, az = 0.f, aw = 0.f;
    for (int e = e0; e < e1; ++e) {
        int nbr = rec2[e];
        float4 v = *(const float4*)(in + (size_t)nbr * FIN + ch * 4);
        ax += v.x; ay += v.y; az += v.z; aw += v.w;
    }
    float sc = rev ? c * dinv_in[node] : c;
    ax *= sc; ay *= sc; az *= sc; aw *= sc;

    size_t o = (size_t)node * FIN + ch * 4;
    if (prevF) {
        float4 p = *(const float4*)((rev ? prevR : prevF) + o);
        ax -= p.x; ay -= p.y; az -= p.z; aw -= p.w;
    }
    float4 res = make_float4(ax, ay, az, aw);
    *(float4*)((rev ? outR : outF) + o) = res;
    if (!rev && gOut) {
        float g = dinv_out[node];
        res.x *= g; res.y *= g; res.z *= g; res.w *= g;
        *(float4*)(gOut + o) = res;
    }
}

// ---------------- epilogue ----------------

__global__ void k_init_out(float* __restrict__ out, const float* __restrict__ b_lin) {
    int t = blockIdx.x * 256 + threadIdx.x;
    if (t < GG * CC) out[t] = b_lin[t & 3];
}

// Per-node: [1x108] @ [108x32] for z and h_tilde, gate, ReLU, @W_lin,
// block-reduce over 250 nodes (each block owns 1/4 of one graph) -> atomicAdd.
__global__ __launch_bounds__(256) void k_fused(
        const float* __restrict__ x, const float* __restrict__ TS,
        const float* __restrict__ Wz, const float* __restrict__ Wh,
        const float* __restrict__ bz, const float* __restrict__ bh,
        const float* __restrict__ Wlin, float* __restrict__ out) {
    int g = blockIdx.x >> 2;
    int seg = blockIdx.x & 3;
    int tid = threadIdx.x;
    int node = g * 1000 + seg * 250 + tid;
    bool active = tid < 250;

    float az[FOUT], ah[FOUT];
#pragma unroll
    for (int f = 0; f < FOUT; ++f) { az[f] = bz[f]; ah[f] = bh[f]; }
    float o[CC] = {0.f, 0.f, 0.f, 0.f};

    if (active) {
        for (int b = 0; b < 9; ++b) {
            const float* row = (b == 0) ? (x + (size_t)node * FIN)
                                        : (TS + ((size_t)(b - 1) * NN + node) * FIN);
            float4 r0 = *(const float4*)(row);
            float4 r1 = *(const float4*)(row + 4);
            float4 r2 = *(const float4*)(row + 8);
            float rv[FIN] = {r0.x, r0.y, r0.z, r0.w, r1.x, r1.y, r1.z, r1.w,
                             r2.x, r2.y, r2.z, r2.w};
            const float* wzr = Wz + b * 12 * FOUT;
            const float* whr = Wh + b * 12 * FOUT;
#pragma unroll
            for (int i = 0; i < FIN; ++i) {
                float v = rv[i];
#pragma unroll
                for (int f = 0; f < FOUT; ++f) {
                    az[f] = fmaf(v, wzr[i * FOUT + f], az[f]);
                    ah[f] = fmaf(v, whr[i * FOUT + f], ah[f]);
                }
            }
        }
#pragma unroll
        for (int f = 0; f < FOUT; ++f) {
            float z = 1.f / (1.f + __expf(-az[f]));
            float e2 = __expf(2.f * ah[f]);
            float th = 1.f - 2.f / (e2 + 1.f);   // tanh, overflow-safe
            float hv = (1.f - z) * th;
            hv = fmaxf(hv, 0.f);
#pragma unroll
            for (int c = 0; c < CC; ++c) o[c] = fmaf(hv, Wlin[f * 4 + c], o[c]);
        }
    }

    __shared__ float red[256 * CC];
#pragma unroll
    for (int c = 0; c < CC; ++c) red[tid * CC + c] = o[c];
    __syncthreads();
    for (int st = 128; st > 0; st >>= 1) {
        if (tid < st) {
#pragma unroll
            for (int c = 0; c < CC; ++c) red[tid * CC + c] += red[(tid + st) * CC + c];
        }
        __syncthreads();
    }
    if (tid == 0) {
#pragma unroll
        for (int c = 0; c < CC; ++c) atomicAdd(out + g * CC + c, red[c] * 0.001f);
    }
}

// ---------------- launch ----------------

extern "C" void kernel_launch(void* const* d_in, const int* in_sizes, int n_in,
                              void* d_out, int out_size, void* d_ws, size_t ws_size,
                              hipStream_t stream) {
    const float* x     = (const float*)d_in[0];
    const int*   ei    = (const int*)d_in[1];
    const float* ew    = (const float*)d_in[2];
    // d_in[3] (batch) unused: graphs are exactly 1000 contiguous nodes
    const float* W_z   = (const float*)d_in[4];
    const float* b_z   = (const float*)d_in[5];
    // d_in[6], d_in[7] (W_r, b_r) unused: R only multiplies the zero hidden state
    const float* W_h   = (const float*)d_in[8];
    const float* b_h   = (const float*)d_in[9];
    const float* W_lin = (const float*)d_in[10];
    const float* b_lin = (const float*)d_in[11];
    float* out = (float*)d_out;

    // ---- workspace layout (~62.6 MB) ----
    int*   rec2     = (int*)d_ws;                       // 2*EE ints (12.8 MB)
    float* TS       = (float*)(rec2 + 2 * (size_t)EE);  // 8*N*12 floats (38.4 MB)
    int2*  recA     = (int2*)TS;                        // ALIAS: 2*EE int2 (25.6 MB), dead before gather 1
    float* gA       = TS + (size_t)8 * NN * FIN;        // N*12 (4.8 MB) shadow buffers
    float* gB       = gA + (size_t)NN * FIN;            // N*12
    float* dinv_in  = gB + (size_t)NN * FIN;            // N
    float* dinv_out = dinv_in + NN;                     // N
    float* Wz       = dinv_out + NN;                    // 108*32
    float* Wh       = Wz + ROWS * FOUT;                 // 108*32
    int*   off      = (int*)(Wh + ROWS * FOUT);         // NBINS+1
    int*   gcnt     = off + NBINS + 1;                  // NBINS
    int*   gcur     = gcnt + NBINS;                     // NBINS
    int*   off_node = gcur + NBINS;                     // 2N+1

    float* T1o = TS + (size_t)0 * NN * FIN;
    float* T2o = TS + (size_t)1 * NN * FIN;
    float* T3o = TS + (size_t)2 * NN * FIN;
    float* T4o = TS + (size_t)3 * NN * FIN;
    float* T1i = TS + (size_t)4 * NN * FIN;
    float* T2i = TS + (size_t)5 * NN * FIN;
    float* T3i = TS + (size_t)6 * NN * FIN;
    float* T4i = TS + (size_t)7 * NN * FIN;

    dim3 B(256);
    int nbG = (6 * NN + 255) / 256;

    k_zero<<<(NBINS + 255) / 256, B, 0, stream>>>(gcnt, NBINS);
    k_hist<<<NBC, B, 0, stream>>>(ei, gcnt);
    k_scan<<<1, 1024, 0, stream>>>(gcnt, off, gcur, off_node);
    k_place<<<NBC, B, 0, stream>>>(ei, ew, gcur, recA);
    k_subcsr<<<NBINS, B, 0, stream>>>(off, recA, x, off_node, rec2, dinv_in, dinv_out, gA);

    k_buildw<<<(2 * ROWS * FOUT + 255) / 256, B, 0, stream>>>(W_z, W_h, Wz, Wh);

    // Chebyshev diffusion basis: per-node gather, pre-scaled fwd inputs (gA/gB)
    k_gather<<<nbG, B, 0, stream>>>(off_node, rec2, gA, x,   nullptr, nullptr, dinv_in, dinv_out, T1o, T1i, gB, 1.f);
    k_gather<<<nbG, B, 0, stream>>>(off_node, rec2, gB, T1i, x,       x,       dinv_in, dinv_out, T2o, T2i, gA, 2.f);
    k_gather<<<nbG, B, 0, stream>>>(off_node, rec2, gA, T2i, T1o,     T1i,     dinv_in, dinv_out, T3o, T3i, gB, 2.f);
    k_gather<<<nbG, B, 0, stream>>>(off_node, rec2, gB, T3i, T2o,     T2i,     dinv_in, dinv_out, T4o, T4i, nullptr, 2.f);

    k_init_out<<<(GG * CC + 255) / 256, B, 0, stream>>>(out, b_lin);
    k_fused<<<4 * GG, B, 0, stream>>>(x, TS, Wz, Wh, b_z, b_h, W_lin, out);
}

// Round 7
// 521.311 us; speedup vs baseline: 2.1966x; 1.0439x over previous
//
#include <hip/hip_runtime.h>
#include <math.h>

#define NN    100000
#define GG    100
#define FIN   12
#define FOUT  32
#define KD    5
#define CC    4
#define EE    1600000
#define ROWS  108          // 9 blocks * 12 features
#define NBF   782          // fwd coarse bins (128 nodes each; last has 96)
#define NBINS 1564         // fwd bins + rev bins
#define NBC   256          // blocks in the coarse build (EE/NBC = 6250 exact)
#define CHUNK 6250
#define NSEG  (NBINS * NBC)   // 400384 = 391 * 1024 exactly

// ---------------- coarse-bucket CSR build ----------------
// Bin layout: bin_f = dst>>7 in [0,NBF); bin_r = NBF + (src>>7).
// recA: .x = nbr | (local_node << 17)  (nbr < 2^17, local < 128), .y = edge weight.

// P1: per-block LDS histogram -> plain stores into bin-major hist_g[bin][blk].
__global__ __launch_bounds__(256) void k_hist(const int* __restrict__ ei,
                                              int* __restrict__ hist_g) {
    __shared__ int hist[NBINS];
    for (int i = threadIdx.x; i < NBINS; i += 256) hist[i] = 0;
    __syncthreads();
    int lo = blockIdx.x * CHUNK, hi = lo + CHUNK;
    for (int e = lo + threadIdx.x; e < hi; e += 256) {
        int s = ei[e], d = ei[EE + e];
        atomicAdd(&hist[d >> 7], 1);
        atomicAdd(&hist[NBF + (s >> 7)], 1);
    }
    __syncthreads();
    for (int i = threadIdx.x; i < NBINS; i += 256)
        hist_g[i * NBC + blockIdx.x] = hist[i];
}

// P2: 3-kernel exclusive scan of hist_g[0..NSEG) in place -> per-(bin,blk) bases.
__global__ __launch_bounds__(1024) void k_scan1(int* __restrict__ g,
                                                int* __restrict__ bsum) {
    __shared__ int sh[1024];
    int t = threadIdx.x;
    int i = blockIdx.x * 1024 + t;
    int v = g[i];                      // NSEG is an exact multiple of 1024
    sh[t] = v;
    __syncthreads();
    for (int d = 1; d < 1024; d <<= 1) {
        int x = sh[t];
        if (t >= d) x += sh[t - d];
        __syncthreads();
        sh[t] = x;
        __syncthreads();
    }
    g[i] = sh[t] - v;
    if (t == 1023) bsum[blockIdx.x] = sh[1023];
}

__global__ __launch_bounds__(1024) void k_scan2(int* __restrict__ bsum, int nb) {
    __shared__ int sh[1024];
    int t = threadIdx.x;
    int v = (t < nb) ? bsum[t] : 0;
    sh[t] = v;
    __syncthreads();
    for (int d = 1; d < 1024; d <<= 1) {
        int x = sh[t];
        if (t >= d) x += sh[t - d];
        __syncthreads();
        sh[t] = x;
        __syncthreads();
    }
    if (t < nb) bsum[t] = sh[t] - v;   // exclusive block base
}

// adds block base; extracts bucket offsets off[bin] = scanned[bin*NBC];
// terminates off/off_node with the constant total 2*EE.
__global__ __launch_bounds__(1024) void k_scan3(int* __restrict__ g,
                                                const int* __restrict__ bsum,
                                                int* __restrict__ off,
                                                int* __restrict__ off_node) {
    int i = blockIdx.x * 1024 + threadIdx.x;
    int v = g[i] + bsum[blockIdx.x];
    g[i] = v;
    if ((i & (NBC - 1)) == 0) off[i / NBC] = v;
    if (i == 0) { off[NBINS] = 2 * EE; off_node[2 * NN] = 2 * EE; }
}

// P3: seed LDS cursors from precomputed bases, place records. No re-histogram,
// no global atomics.
__global__ __launch_bounds__(256) void k_place(const int* __restrict__ ei,
                                               const float* __restrict__ ew,
                                               const int* __restrict__ base_g,
                                               int2* __restrict__ recA) {
    __shared__ int cur[NBINS];
    int b = blockIdx.x;
    for (int i = threadIdx.x; i < NBINS; i += 256) cur[i] = base_g[i * NBC + b];
    __syncthreads();
    int lo = b * CHUNK, hi = lo + CHUNK;
    for (int e = lo + threadIdx.x; e < hi; e += 256) {
        int s = ei[e], d = ei[EE + e];
        float w = ew[e];
        int pf = atomicAdd(&cur[d >> 7], 1);
        recA[pf] = make_int2(s | ((d & 127) << 17), __float_as_int(w));
        int pr = atomicAdd(&cur[NBF + (s >> 7)], 1);
        recA[pr] = make_int2(d | ((s & 127) << 17), __float_as_int(w));
    }
}

// P4: per-bin counting sort by local node -> exact per-node CSR (4B records),
// fused weighted-degree sums -> dinv, and (rev bins) gA = dinv_out .* x.
__global__ __launch_bounds__(256) void k_subcsr(
        const int* __restrict__ off, const int2* __restrict__ recA,
        const float* __restrict__ x,
        int* __restrict__ off_node, int* __restrict__ rec2,
        float* __restrict__ dinv_in, float* __restrict__ dinv_out,
        float* __restrict__ gA) {
    __shared__ int   hist[128];
    __shared__ int   lofs[128];
    __shared__ int   cur[128];
    __shared__ float wsum[128];
    __shared__ float dl[128];
    int b = blockIdx.x;
    int t = threadIdx.x;
    if (t < 128) { hist[t] = 0; wsum[t] = 0.f; }
    __syncthreads();
    int e0 = off[b], e1 = off[b + 1];
    for (int e = e0 + t; e < e1; e += 256) {
        int2 r = recA[e];
        int loc = r.x >> 17;
        atomicAdd(&hist[loc], 1);
        atomicAdd(&wsum[loc], __int_as_float(r.y));
    }
    __syncthreads();
    if (t < 128) lofs[t] = hist[t];
    __syncthreads();
    for (int d = 1; d < 128; d <<= 1) {
        int v = 0;
        if (t < 128 && t >= d) v = lofs[t - d];
        __syncthreads();
        if (t < 128) lofs[t] += v;
        __syncthreads();
    }
    bool rev = b >= NBF;
    int base = (rev ? b - NBF : b) * 128;
    if (t < 128) {
        int ex = lofs[t] - hist[t];      // exclusive
        lofs[t] = ex;
        cur[t] = 0;
        int node = base + t;
        if (node < NN) {
            off_node[(rev ? NN : 0) + node] = e0 + ex;
            float inv = 1.f / wsum[t];
            dl[t] = inv;
            if (rev) dinv_out[node] = inv;
            else     dinv_in[node]  = inv;
        }
    }
    __syncthreads();
    for (int e = e0 + t; e < e1; e += 256) {
        int rx = recA[e].x;
        int loc = rx >> 17;
        int pos = e0 + lofs[loc] + atomicAdd(&cur[loc], 1);
        rec2[pos] = rx & 0x1FFFF;
    }
    if (rev) {
        __syncthreads();
        for (int i = t; i < 128 * 3; i += 256) {
            int loc = i / 3, ch = i - loc * 3;
            int node = base + loc;
            if (node < NN) {
                float4 v = *(const float4*)(x + (size_t)node * FIN + ch * 4);
                float sc = dl[loc];
                v.x *= sc; v.y *= sc; v.z *= sc; v.w *= sc;
                *(float4*)(gA + (size_t)node * FIN + ch * 4) = v;
            }
        }
    }
}

// ---------------- weights ----------------

// Collapse W[2,K,44,32] -> effective [108,32] (only first 12 input rows matter;
// block 0 = W[0,0]+W[1,0]; blocks 1..4 = W[0,k]; blocks 5..8 = W[1,k]).
__global__ void k_buildw(const float* __restrict__ Wz_in, const float* __restrict__ Wh_in,
                         float* __restrict__ Wz, float* __restrict__ Wh) {
    int t = blockIdx.x * 256 + threadIdx.x;
    if (t >= 2 * ROWS * FOUT) return;
    int sel = t / (ROWS * FOUT);
    int rem = t - sel * ROWS * FOUT;
    int r = rem / FOUT;
    int f = rem - r * FOUT;
    int b = r / 12;
    int i = r - b * 12;
    const float* Ws = sel ? Wh_in : Wz_in;
    float v;
    if (b == 0)
        v = Ws[(0 * KD + 0) * 44 * 32 + i * 32 + f] + Ws[(1 * KD + 0) * 44 * 32 + i * 32 + f];
    else if (b <= 4)
        v = Ws[(0 * KD + b) * 44 * 32 + i * 32 + f];
    else
        v = Ws[(1 * KD + (b - 4)) * 44 * 32 + i * 32 + f];
    (sel ? Wh : Wz)[r * FOUT + f] = v;
}

// ---------------- diffusion gather ----------------
// Thread per (node, direction, 4-feature chunk); 4B records, no weights:
// fwd: out[n] = c * sum gIn[src]                 - prevF[n];  gOut[n] = dinv_out[n]*out[n]
// rev: out[n] = c * dinv_in[n] * sum hIn[dst]    - prevR[n]
__global__ __launch_bounds__(256) void k_gather(
        const int* __restrict__ off_node, const int* __restrict__ rec2,
        const float* __restrict__ gIn, const float* __restrict__ hIn,
        const float* __restrict__ prevF, const float* __restrict__ prevR,
        const float* __restrict__ dinv_in, const float* __restrict__ dinv_out,
        float* __restrict__ outF, float* __restrict__ outR,
        float* __restrict__ gOut, float c) {
    int gid = blockIdx.x * 256 + threadIdx.x;
    if (gid >= 6 * NN) return;
    bool rev = gid >= 3 * NN;
    int t = rev ? gid - 3 * NN : gid;
    int node = t / 3;
    int ch = t - node * 3;
    int i0 = (rev ? NN : 0) + node;
    int e0 = off_node[i0], e1 = off_node[i0 + 1];
    const float* in = rev ? hIn : gIn;

    float ax = 0.f, ay = 0.f, az = 0.f, aw = 0.f;
    for (int e = e0; e < e1; ++e) {
        int nbr = rec2[e];
        float4 v = *(const float4*)(in + (size_t)nbr * FIN + ch * 4);
        ax += v.x; ay += v.y; az += v.z; aw += v.w;
    }
    float sc = rev ? c * dinv_in[node] : c;
    ax *= sc; ay *= sc; az *= sc; aw *= sc;

    size_t o = (size_t)node * FIN + ch * 4;
    if (prevF) {
        float4 p = *(const float4*)((rev ? prevR : prevF) + o);
        ax -= p.x; ay -= p.y; az -= p.z; aw -= p.w;
    }
    float4 res = make_float4(ax, ay, az, aw);
    *(float4*)((rev ? outR : outF) + o) = res;
    if (!rev && gOut) {
        float g = dinv_out[node];
        res.x *= g; res.y *= g; res.z *= g; res.w *= g;
        *(float4*)(gOut + o) = res;
    }
}

// ---------------- epilogue ----------------

__global__ void k_init_out(float* __restrict__ out, const float* __restrict__ b_lin) {
    int t = blockIdx.x * 256 + threadIdx.x;
    if (t < GG * CC) out[t] = b_lin[t & 3];
}

// Per-node: [1x108] @ [108x32] for z and h_tilde, gate, ReLU, @W_lin,
// block-reduce over 250 nodes (each block owns 1/4 of one graph) -> atomicAdd.
__global__ __launch_bounds__(256) void k_fused(
        const float* __restrict__ x, const float* __restrict__ TS,
        const float* __restrict__ Wz, const float* __restrict__ Wh,
        const float* __restrict__ bz, const float* __restrict__ bh,
        const float* __restrict__ Wlin, float* __restrict__ out) {
    int g = blockIdx.x >> 2;
    int seg = blockIdx.x & 3;
    int tid = threadIdx.x;
    int node = g * 1000 + seg * 250 + tid;
    bool active = tid < 250;

    float az[FOUT], ah[FOUT];
#pragma unroll
    for (int f = 0; f < FOUT; ++f) { az[f] = bz[f]; ah[f] = bh[f]; }
    float o[CC] = {0.f, 0.f, 0.f, 0.f};

    if (active) {
        for (int b = 0; b < 9; ++b) {
            const float* row = (b == 0) ? (x + (size_t)node * FIN)
                                        : (TS + ((size_t)(b - 1) * NN + node) * FIN);
            float4 r0 = *(const float4*)(row);
            float4 r1 = *(const float4*)(row + 4);
            float4 r2 = *(const float4*)(row + 8);
            float rv[FIN] = {r0.x, r0.y, r0.z, r0.w, r1.x, r1.y, r1.z, r1.w,
                             r2.x, r2.y, r2.z, r2.w};
            const float* wzr = Wz + b * 12 * FOUT;
            const float* whr = Wh + b * 12 * FOUT;
#pragma unroll
            for (int i = 0; i < FIN; ++i) {
                float v = rv[i];
#pragma unroll
                for (int f = 0; f < FOUT; ++f) {
                    az[f] = fmaf(v, wzr[i * FOUT + f], az[f]);
                    ah[f] = fmaf(v, whr[i * FOUT + f], ah[f]);
                }
            }
        }
#pragma unroll
        for (int f = 0; f < FOUT; ++f) {
            float z = 1.f / (1.f + __expf(-az[f]));
            float e2 = __expf(2.f * ah[f]);
            float th = 1.f - 2.f / (e2 + 1.f);   // tanh, overflow-safe
            float hv = (1.f - z) * th;
            hv = fmaxf(hv, 0.f);
#pragma unroll
            for (int c = 0; c < CC; ++c) o[c] = fmaf(hv, Wlin[f * 4 + c], o[c]);
        }
    }

    __shared__ float red[256 * CC];
#pragma unroll
    for (int c = 0; c < CC; ++c) red[tid * CC + c] = o[c];
    __syncthreads();
    for (int st = 128; st > 0; st >>= 1) {
        if (tid < st) {
#pragma unroll
            for (int c = 0; c < CC; ++c) red[tid * CC + c] += red[(tid + st) * CC + c];
        }
        __syncthreads();
    }
    if (tid == 0) {
#pragma unroll
        for (int c = 0; c < CC; ++c) atomicAdd(out + g * CC + c, red[c] * 0.001f);
    }
}

// ---------------- launch ----------------

extern "C" void kernel_launch(void* const* d_in, const int* in_sizes, int n_in,
                              void* d_out, int out_size, void* d_ws, size_t ws_size,
                              hipStream_t stream) {
    const float* x     = (const float*)d_in[0];
    const int*   ei    = (const int*)d_in[1];
    const float* ew    = (const float*)d_in[2];
    // d_in[3] (batch) unused: graphs are exactly 1000 contiguous nodes
    const float* W_z   = (const float*)d_in[4];
    const float* b_z   = (const float*)d_in[5];
    // d_in[6], d_in[7] (W_r, b_r) unused: R only multiplies the zero hidden state
    const float* W_h   = (const float*)d_in[8];
    const float* b_h   = (const float*)d_in[9];
    const float* W_lin = (const float*)d_in[10];
    const float* b_lin = (const float*)d_in[11];
    float* out = (float*)d_out;

    // ---- workspace layout (~64.3 MB) ----
    int*   rec2     = (int*)d_ws;                       // 2*EE ints (12.8 MB)
    float* TS       = (float*)(rec2 + 2 * (size_t)EE);  // 8*N*12 floats (38.4 MB)
    int2*  recA     = (int2*)TS;                        // ALIAS: 2*EE int2 (25.6 MB), dead before gather 1
    float* gA       = TS + (size_t)8 * NN * FIN;        // N*12 (4.8 MB) shadow buffers
    float* gB       = gA + (size_t)NN * FIN;            // N*12
    float* dinv_in  = gB + (size_t)NN * FIN;            // N
    float* dinv_out = dinv_in + NN;                     // N
    float* Wz       = dinv_out + NN;                    // 108*32
    float* Wh       = Wz + ROWS * FOUT;                 // 108*32
    int*   off      = (int*)(Wh + ROWS * FOUT);         // NBINS+1
    int*   off_node = off + NBINS + 1;                  // 2N+1
    int*   hist_g   = off_node + 2 * NN + 1;            // NSEG (1.6 MB)
    int*   bsumS    = hist_g + NSEG;                    // NSEG/1024 = 391

    float* T1o = TS + (size_t)0 * NN * FIN;
    float* T2o = TS + (size_t)1 * NN * FIN;
    float* T3o = TS + (size_t)2 * NN * FIN;
    float* T4o = TS + (size_t)3 * NN * FIN;
    float* T1i = TS + (size_t)4 * NN * FIN;
    float* T2i = TS + (size_t)5 * NN * FIN;
    float* T3i = TS + (size_t)6 * NN * FIN;
    float* T4i = TS + (size_t)7 * NN * FIN;

    dim3 B(256);
    int nbG = (6 * NN + 255) / 256;
    int nbScan = NSEG / 1024;                  // 391, exact

    k_hist<<<NBC, B, 0, stream>>>(ei, hist_g);
    k_scan1<<<nbScan, 1024, 0, stream>>>(hist_g, bsumS);
    k_scan2<<<1, 1024, 0, stream>>>(bsumS, nbScan);
    k_scan3<<<nbScan, 1024, 0, stream>>>(hist_g, bsumS, off, off_node);
    k_place<<<NBC, B, 0, stream>>>(ei, ew, hist_g, recA);
    k_subcsr<<<NBINS, B, 0, stream>>>(off, recA, x, off_node, rec2, dinv_in, dinv_out, gA);

    k_buildw<<<(2 * ROWS * FOUT + 255) / 256, B, 0, stream>>>(W_z, W_h, Wz, Wh);

    // Chebyshev diffusion basis: per-node gather, pre-scaled fwd inputs (gA/gB)
    k_gather<<<nbG, B, 0, stream>>>(off_node, rec2, gA, x,   nullptr, nullptr, dinv_in, dinv_out, T1o, T1i, gB, 1.f);
    k_gather<<<nbG, B, 0, stream>>>(off_node, rec2, gB, T1i, x,       x,       dinv_in, dinv_out, T2o, T2i, gA, 2.f);
    k_gather<<<nbG, B, 0, stream>>>(off_node, rec2, gA, T2i, T1o,     T1i,     dinv_in, dinv_out, T3o, T3i, gB, 2.f);
    k_gather<<<nbG, B, 0, stream>>>(off_node, rec2, gB, T3i, T2o,     T2i,     dinv_in, dinv_out, T4o, T4i, nullptr, 2.f);

    k_init_out<<<(GG * CC + 255) / 256, B, 0, stream>>>(out, b_lin);
    k_fused<<<4 * GG, B, 0, stream>>>(x, TS, Wz, Wh, b_z, b_h, W_lin, out);
}

// Round 8
// 399.066 us; speedup vs baseline: 2.8695x; 1.3063x over previous
//
#include <hip/hip_runtime.h>
#include <math.h>

#define NN    100000
#define GG    100
#define FIN   12
#define FOUT  32
#define KD    5
#define CC    4
#define EE    1600000
#define ROWS  108          // 9 blocks * 12 features
#define NBF   782          // fwd coarse bins (128 nodes each; last has 96)
#define NBINS 1564         // fwd bins + rev bins
#define NBC   256          // blocks in the coarse build (EE/NBC = 6250 exact)
#define CHUNK 6250
#define NSEG  (NBINS * NBC)   // 400384 = 391 * 1024 exactly

// ---------------- coarse-bucket CSR build ----------------
// Bin layout: bin_f = dst>>7 in [0,NBF); bin_r = NBF + (src>>7).
// recA: .x = nbr | (local_node << 17)  (nbr < 2^17, local < 128), .y = edge weight.

// P1: per-block LDS histogram -> plain stores into bin-major hist_g[bin][blk].
__global__ __launch_bounds__(256) void k_hist(const int* __restrict__ ei,
                                              int* __restrict__ hist_g) {
    __shared__ int hist[NBINS];
    for (int i = threadIdx.x; i < NBINS; i += 256) hist[i] = 0;
    __syncthreads();
    int lo = blockIdx.x * CHUNK, hi = lo + CHUNK;
    for (int e = lo + threadIdx.x; e < hi; e += 256) {
        int s = ei[e], d = ei[EE + e];
        atomicAdd(&hist[d >> 7], 1);
        atomicAdd(&hist[NBF + (s >> 7)], 1);
    }
    __syncthreads();
    for (int i = threadIdx.x; i < NBINS; i += 256)
        hist_g[i * NBC + blockIdx.x] = hist[i];
}

// P2: 3-kernel exclusive scan of hist_g[0..NSEG) in place -> per-(bin,blk) bases.
__global__ __launch_bounds__(1024) void k_scan1(int* __restrict__ g,
                                                int* __restrict__ bsum) {
    __shared__ int sh[1024];
    int t = threadIdx.x;
    int i = blockIdx.x * 1024 + t;
    int v = g[i];                      // NSEG is an exact multiple of 1024
    sh[t] = v;
    __syncthreads();
    for (int d = 1; d < 1024; d <<= 1) {
        int x = sh[t];
        if (t >= d) x += sh[t - d];
        __syncthreads();
        sh[t] = x;
        __syncthreads();
    }
    g[i] = sh[t] - v;
    if (t == 1023) bsum[blockIdx.x] = sh[1023];
}

__global__ __launch_bounds__(1024) void k_scan2(int* __restrict__ bsum, int nb) {
    __shared__ int sh[1024];
    int t = threadIdx.x;
    int v = (t < nb) ? bsum[t] : 0;
    sh[t] = v;
    __syncthreads();
    for (int d = 1; d < 1024; d <<= 1) {
        int x = sh[t];
        if (t >= d) x += sh[t - d];
        __syncthreads();
        sh[t] = x;
        __syncthreads();
    }
    if (t < nb) bsum[t] = sh[t] - v;   // exclusive block base
}

// adds block base; extracts bucket offsets off[bin] = scanned[bin*NBC];
// terminates off/off_node with the constant total 2*EE.
__global__ __launch_bounds__(1024) void k_scan3(int* __restrict__ g,
                                                const int* __restrict__ bsum,
                                                int* __restrict__ off,
                                                int* __restrict__ off_node) {
    int i = blockIdx.x * 1024 + threadIdx.x;
    int v = g[i] + bsum[blockIdx.x];
    g[i] = v;
    if ((i & (NBC - 1)) == 0) off[i / NBC] = v;
    if (i == 0) { off[NBINS] = 2 * EE; off_node[2 * NN] = 2 * EE; }
}

// P3: seed LDS cursors from precomputed bases, place records. No re-histogram,
// no global atomics.
__global__ __launch_bounds__(256) void k_place(const int* __restrict__ ei,
                                               const float* __restrict__ ew,
                                               const int* __restrict__ base_g,
                                               int2* __restrict__ recA) {
    __shared__ int cur[NBINS];
    int b = blockIdx.x;
    for (int i = threadIdx.x; i < NBINS; i += 256) cur[i] = base_g[i * NBC + b];
    __syncthreads();
    int lo = b * CHUNK, hi = lo + CHUNK;
    for (int e = lo + threadIdx.x; e < hi; e += 256) {
        int s = ei[e], d = ei[EE + e];
        float w = ew[e];
        int pf = atomicAdd(&cur[d >> 7], 1);
        recA[pf] = make_int2(s | ((d & 127) << 17), __float_as_int(w));
        int pr = atomicAdd(&cur[NBF + (s >> 7)], 1);
        recA[pr] = make_int2(d | ((s & 127) << 17), __float_as_int(w));
    }
}

// P4: per-bin counting sort by local node -> exact per-node CSR (4B records),
// fused weighted-degree sums -> dinv, and (rev bins) gA = dinv_out .* x.
__global__ __launch_bounds__(256) void k_subcsr(
        const int* __restrict__ off, const int2* __restrict__ recA,
        const float* __restrict__ x,
        int* __restrict__ off_node, int* __restrict__ rec2,
        float* __restrict__ dinv_in, float* __restrict__ dinv_out,
        float* __restrict__ gA) {
    __shared__ int   hist[128];
    __shared__ int   lofs[128];
    __shared__ int   cur[128];
    __shared__ float wsum[128];
    __shared__ float dl[128];
    int b = blockIdx.x;
    int t = threadIdx.x;
    if (t < 128) { hist[t] = 0; wsum[t] = 0.f; }
    __syncthreads();
    int e0 = off[b], e1 = off[b + 1];
    for (int e = e0 + t; e < e1; e += 256) {
        int2 r = recA[e];
        int loc = r.x >> 17;
        atomicAdd(&hist[loc], 1);
        atomicAdd(&wsum[loc], __int_as_float(r.y));
    }
    __syncthreads();
    if (t < 128) lofs[t] = hist[t];
    __syncthreads();
    for (int d = 1; d < 128; d <<= 1) {
        int v = 0;
        if (t < 128 && t >= d) v = lofs[t - d];
        __syncthreads();
        if (t < 128) lofs[t] += v;
        __syncthreads();
    }
    bool rev = b >= NBF;
    int base = (rev ? b - NBF : b) * 128;
    if (t < 128) {
        int ex = lofs[t] - hist[t];      // exclusive
        lofs[t] = ex;
        cur[t] = 0;
        int node = base + t;
        if (node < NN) {
            off_node[(rev ? NN : 0) + node] = e0 + ex;
            float inv = 1.f / wsum[t];
            dl[t] = inv;
            if (rev) dinv_out[node] = inv;
            else     dinv_in[node]  = inv;
        }
    }
    __syncthreads();
    for (int e = e0 + t; e < e1; e += 256) {
        int rx = recA[e].x;
        int loc = rx >> 17;
        int pos = e0 + lofs[loc] + atomicAdd(&cur[loc], 1);
        rec2[pos] = rx & 0x1FFFF;
    }
    if (rev) {
        __syncthreads();
        for (int i = t; i < 128 * 3; i += 256) {
            int loc = i / 3, ch = i - loc * 3;
            int node = base + loc;
            if (node < NN) {
                float4 v = *(const float4*)(x + (size_t)node * FIN + ch * 4);
                float sc = dl[loc];
                v.x *= sc; v.y *= sc; v.z *= sc; v.w *= sc;
                *(float4*)(gA + (size_t)node * FIN + ch * 4) = v;
            }
        }
    }
}

// ---------------- weights ----------------

// Collapse W[2,K,44,32] -> effective [108,32] (only first 12 input rows matter;
// block 0 = W[0,0]+W[1,0]; blocks 1..4 = W[0,k]; blocks 5..8 = W[1,k]).
__global__ void k_buildw(const float* __restrict__ Wz_in, const float* __restrict__ Wh_in,
                         float* __restrict__ Wz, float* __restrict__ Wh) {
    int t = blockIdx.x * 256 + threadIdx.x;
    if (t >= 2 * ROWS * FOUT) return;
    int sel = t / (ROWS * FOUT);
    int rem = t - sel * ROWS * FOUT;
    int r = rem / FOUT;
    int f = rem - r * FOUT;
    int b = r / 12;
    int i = r - b * 12;
    const float* Ws = sel ? Wh_in : Wz_in;
    float v;
    if (b == 0)
        v = Ws[(0 * KD + 0) * 44 * 32 + i * 32 + f] + Ws[(1 * KD + 0) * 44 * 32 + i * 32 + f];
    else if (b <= 4)
        v = Ws[(0 * KD + b) * 44 * 32 + i * 32 + f];
    else
        v = Ws[(1 * KD + (b - 4)) * 44 * 32 + i * 32 + f];
    (sel ? Wh : Wz)[r * FOUT + f] = v;
}

// ---------------- diffusion gather ----------------
// XCD-partitioned: blocks with (blockIdx&7) in 0..3 do fwd nodes, 4..7 do rev.
// Each XCD's random-read working set is then ONE 4.8 MB array (fits its 4 MB L2
// much better than the 9.6 MB mixed set). Grid 2344 = 293*8; 1172 blocks/role
// = exactly 3N/256 threads. Heuristic only — correctness is role-independent.
// fwd: out[n] = c * sum gIn[src]                 - prevF[n];  gOut[n] = dinv_out[n]*out[n]
// rev: out[n] = c * dinv_in[n] * sum hIn[dst]    - prevR[n]
__global__ __launch_bounds__(256) void k_gather(
        const int* __restrict__ off_node, const int* __restrict__ rec2,
        const float* __restrict__ gIn, const float* __restrict__ hIn,
        const float* __restrict__ prevF, const float* __restrict__ prevR,
        const float* __restrict__ dinv_in, const float* __restrict__ dinv_out,
        float* __restrict__ outF, float* __restrict__ outR,
        float* __restrict__ gOut, float c) {
    int xcd = blockIdx.x & 7;
    int grp = blockIdx.x >> 3;             // 0..292
    bool rev = xcd >= 4;
    int lin = (grp * 4 + (xcd & 3)) * 256 + threadIdx.x;
    if (lin >= 3 * NN) return;
    int node = lin / 3;
    int ch = lin - node * 3;
    int i0 = (rev ? NN : 0) + node;
    int e0 = off_node[i0], e1 = off_node[i0 + 1];
    const float* in = rev ? hIn : gIn;

    // 2-way unrolled, independent accumulators (more loads in flight per waitcnt)
    float ax = 0.f, ay = 0.f, az = 0.f, aw = 0.f;
    float bx = 0.f, by = 0.f, bz = 0.f, bw = 0.f;
    int e = e0;
    for (; e + 1 < e1; e += 2) {
        int n0 = rec2[e], n1 = rec2[e + 1];
        float4 v0 = *(const float4*)(in + (size_t)n0 * FIN + ch * 4);
        float4 v1 = *(const float4*)(in + (size_t)n1 * FIN + ch * 4);
        ax += v0.x; ay += v0.y; az += v0.z; aw += v0.w;
        bx += v1.x; by += v1.y; bz += v1.z; bw += v1.w;
    }
    if (e < e1) {
        int n0 = rec2[e];
        float4 v0 = *(const float4*)(in + (size_t)n0 * FIN + ch * 4);
        ax += v0.x; ay += v0.y; az += v0.z; aw += v0.w;
    }
    ax += bx; ay += by; az += bz; aw += bw;

    float sc = rev ? c * dinv_in[node] : c;
    ax *= sc; ay *= sc; az *= sc; aw *= sc;

    size_t o = (size_t)node * FIN + ch * 4;
    if (prevF) {
        float4 p = *(const float4*)((rev ? prevR : prevF) + o);
        ax -= p.x; ay -= p.y; az -= p.z; aw -= p.w;
    }
    float4 res = make_float4(ax, ay, az, aw);
    *(float4*)((rev ? outR : outF) + o) = res;
    if (!rev && gOut) {
        float g = dinv_out[node];
        res.x *= g; res.y *= g; res.z *= g; res.w *= g;
        *(float4*)(gOut + o) = res;
    }
}

// ---------------- epilogue ----------------

__global__ void k_init_out(float* __restrict__ out, const float* __restrict__ b_lin) {
    int t = blockIdx.x * 256 + threadIdx.x;
    if (t < GG * CC) out[t] = b_lin[t & 3];
}

// Per-node: [1x108] @ [108x32] for z and h_tilde, gate, ReLU, @W_lin,
// block-reduce over 250 nodes (each block owns 1/4 of one graph) -> atomicAdd.
__global__ __launch_bounds__(256) void k_fused(
        const float* __restrict__ x, const float* __restrict__ TS,
        const float* __restrict__ Wz, const float* __restrict__ Wh,
        const float* __restrict__ bz, const float* __restrict__ bh,
        const float* __restrict__ Wlin, float* __restrict__ out) {
    int g = blockIdx.x >> 2;
    int seg = blockIdx.x & 3;
    int tid = threadIdx.x;
    int node = g * 1000 + seg * 250 + tid;
    bool active = tid < 250;

    float az[FOUT], ah[FOUT];
#pragma unroll
    for (int f = 0; f < FOUT; ++f) { az[f] = bz[f]; ah[f] = bh[f]; }
    float o[CC] = {0.f, 0.f, 0.f, 0.f};

    if (active) {
        for (int b = 0; b < 9; ++b) {
            const float* row = (b == 0) ? (x + (size_t)node * FIN)
                                        : (TS + ((size_t)(b - 1) * NN + node) * FIN);
            float4 r0 = *(const float4*)(row);
            float4 r1 = *(const float4*)(row + 4);
            float4 r2 = *(const float4*)(row + 8);
            float rv[FIN] = {r0.x, r0.y, r0.z, r0.w, r1.x, r1.y, r1.z, r1.w,
                             r2.x, r2.y, r2.z, r2.w};
            const float* wzr = Wz + b * 12 * FOUT;
            const float* whr = Wh + b * 12 * FOUT;
#pragma unroll
            for (int i = 0; i < FIN; ++i) {
                float v = rv[i];
#pragma unroll
                for (int f = 0; f < FOUT; ++f) {
                    az[f] = fmaf(v, wzr[i * FOUT + f], az[f]);
                    ah[f] = fmaf(v, whr[i * FOUT + f], ah[f]);
                }
            }
        }
#pragma unroll
        for (int f = 0; f < FOUT; ++f) {
            float z = 1.f / (1.f + __expf(-az[f]));
            float e2 = __expf(2.f * ah[f]);
            float th = 1.f - 2.f / (e2 + 1.f);   // tanh, overflow-safe
            float hv = (1.f - z) * th;
            hv = fmaxf(hv, 0.f);
#pragma unroll
            for (int c = 0; c < CC; ++c) o[c] = fmaf(hv, Wlin[f * 4 + c], o[c]);
        }
    }

    __shared__ float red[256 * CC];
#pragma unroll
    for (int c = 0; c < CC; ++c) red[tid * CC + c] = o[c];
    __syncthreads();
    for (int st = 128; st > 0; st >>= 1) {
        if (tid < st) {
#pragma unroll
            for (int c = 0; c < CC; ++c) red[tid * CC + c] += red[(tid + st) * CC + c];
        }
        __syncthreads();
    }
    if (tid == 0) {
#pragma unroll
        for (int c = 0; c < CC; ++c) atomicAdd(out + g * CC + c, red[c] * 0.001f);
    }
}

// ---------------- launch ----------------

extern "C" void kernel_launch(void* const* d_in, const int* in_sizes, int n_in,
                              void* d_out, int out_size, void* d_ws, size_t ws_size,
                              hipStream_t stream) {
    const float* x     = (const float*)d_in[0];
    const int*   ei    = (const int*)d_in[1];
    const float* ew    = (const float*)d_in[2];
    // d_in[3] (batch) unused: graphs are exactly 1000 contiguous nodes
    const float* W_z   = (const float*)d_in[4];
    const float* b_z   = (const float*)d_in[5];
    // d_in[6], d_in[7] (W_r, b_r) unused: R only multiplies the zero hidden state
    const float* W_h   = (const float*)d_in[8];
    const float* b_h   = (const float*)d_in[9];
    const float* W_lin = (const float*)d_in[10];
    const float* b_lin = (const float*)d_in[11];
    float* out = (float*)d_out;

    // ---- workspace layout (~64.3 MB) ----
    int*   rec2     = (int*)d_ws;                       // 2*EE ints (12.8 MB)
    float* TS       = (float*)(rec2 + 2 * (size_t)EE);  // 8*N*12 floats (38.4 MB)
    int2*  recA     = (int2*)TS;                        // ALIAS: 2*EE int2 (25.6 MB), dead before gather 1
    float* gA       = TS + (size_t)8 * NN * FIN;        // N*12 (4.8 MB) shadow buffers
    float* gB       = gA + (size_t)NN * FIN;            // N*12
    float* dinv_in  = gB + (size_t)NN * FIN;            // N
    float* dinv_out = dinv_in + NN;                     // N
    float* Wz       = dinv_out + NN;                    // 108*32
    float* Wh       = Wz + ROWS * FOUT;                 // 108*32
    int*   off      = (int*)(Wh + ROWS * FOUT);         // NBINS+1
    int*   off_node = off + NBINS + 1;                  // 2N+1
    int*   hist_g   = off_node + 2 * NN + 1;            // NSEG (1.6 MB)
    int*   bsumS    = hist_g + NSEG;                    // NSEG/1024 = 391

    float* T1o = TS + (size_t)0 * NN * FIN;
    float* T2o = TS + (size_t)1 * NN * FIN;
    float* T3o = TS + (size_t)2 * NN * FIN;
    float* T4o = TS + (size_t)3 * NN * FIN;
    float* T1i = TS + (size_t)4 * NN * FIN;
    float* T2i = TS + (size_t)5 * NN * FIN;
    float* T3i = TS + (size_t)6 * NN * FIN;
    float* T4i = TS + (size_t)7 * NN * FIN;

    dim3 B(256);
    int nbG = 2344;                            // 293 * 8 — exact for the XCD swizzle
    int nbScan = NSEG / 1024;                  // 391, exact

    k_hist<<<NBC, B, 0, stream>>>(ei, hist_g);
    k_scan1<<<nbScan, 1024, 0, stream>>>(hist_g, bsumS);
    k_scan2<<<1, 1024, 0, stream>>>(bsumS, nbScan);
    k_scan3<<<nbScan, 1024, 0, stream>>>(hist_g, bsumS, off, off_node);
    k_place<<<NBC, B, 0, stream>>>(ei, ew, hist_g, recA);
    k_subcsr<<<NBINS, B, 0, stream>>>(off, recA, x, off_node, rec2, dinv_in, dinv_out, gA);

    k_buildw<<<(2 * ROWS * FOUT + 255) / 256, B, 0, stream>>>(W_z, W_h, Wz, Wh);

    // Chebyshev diffusion basis: per-node gather, pre-scaled fwd inputs (gA/gB)
    k_gather<<<nbG, B, 0, stream>>>(off_node, rec2, gA, x,   nullptr, nullptr, dinv_in, dinv_out, T1o, T1i, gB, 1.f);
    k_gather<<<nbG, B, 0, stream>>>(off_node, rec2, gB, T1i, x,       x,       dinv_in, dinv_out, T2o, T2i, gA, 2.f);
    k_gather<<<nbG, B, 0, stream>>>(off_node, rec2, gA, T2i, T1o,     T1i,     dinv_in, dinv_out, T3o, T3i, gB, 2.f);
    k_gather<<<nbG, B, 0, stream>>>(off_node, rec2, gB, T3i, T2o,     T2i,     dinv_in, dinv_out, T4o, T4i, nullptr, 2.f);

    k_init_out<<<(GG * CC + 255) / 256, B, 0, stream>>>(out, b_lin);
    k_fused<<<4 * GG, B, 0, stream>>>(x, TS, Wz, Wh, b_z, b_h, W_lin, out);
}